// Round 9
// baseline (813.430 us; speedup 1.0000x reference)
//
#include <hip/hip_runtime.h>
#include <stdint.h>

// ProgressiveVQ: 8-stage residual VQ, T=131072 rows, D=256, K=1024 codewords/stage.
// out[0:T*D] = recon ; out[T*D..+8] = per-stage MSE (= mean(residual_i^2)).
//
// R9: r=2 ratio at R8's de-correlated geometry.
//   Model (validated by R8): matrix demand 512 cyc/chunk/SIMD; LDS fabric
//   256 B/cyc. r=1@16 waves: 1280 LDS cyc -> 40% ceiling (R8 measured 40.8 —
//   ON the LDS roofline). r=2@8 waves: 768 cyc -> 67% ceiling, R1 measured
//   40 -> sync/convoy-bound. Fix the convoy, keep r=2:
//   * 128-thread / 2-WAVE blocks, grid 1024 -> 4 blocks/CU, 8 waves/CU.
//     Barriers convoy only 2 waves; 4 independent blocks drift out of phase
//     so LDS bursts and MFMA clusters interleave across the CU (R8's
//     demonstrated mechanism, now at half the LDS-read amplification).
//   * Per-wave code = R1's proven no-spill set: af[2][16] (128 VGPR), two
//     f32x16 accs, mv[2][16]. 2 waves/SIMD budget 256 regs — fits (R1: 128).
//   * R8's schedule: 2 x 16 KB ring, depth-1; top-of-chunk barrier; staging
//     for ch+1 issued right after it (that buffer's readers were ch-1, all
//     pre-barrier); own staging drained by vmcnt(0) at the bottom so
//     barrier(ch+1) implies fully staged. Flat B-FRAGMENT layout; cnorm
//     from global (consumed only at pack).
//   * acc zero-init; -||c||^2/2 deferred to pack; fmax-only argmax with the
//     codeword index packed into the low 10 mantissa bits.
//   bf16-carried residual (argmin near-ties only; validated earlier,
//   absmax <=4.5e-3). ||r||^2 recursion gives MSE free.

#define T_ROWS   131072
#define DIM      256
#define NSTAGE   8
#define NCB      1024
#define WROWS    64             // rows per wave (TWO 32-row m-tiles)
#define NWAVE    2
#define BLK_ROWS (NWAVE * WROWS)   // 128 rows per block
#define NTHREADS (NWAVE * 64)      // 128 threads
#define CHUNK_CW 32             // codewords per chunk
#define NCHUNK   (NCB / CHUNK_CW)          // 32 chunks/stage
#define NGCH     (NSTAGE * NCHUNK)         // 256 flat chunks
#define CHUNK_BYTES (CHUNK_CW * 512)       // 16384

// d_ws layout
#define WS_B_BYTES     (NSTAGE * NCB * 512)            // bf16 codebook, B-frag layout, 4 MiB
#define WS_CNORM_OFF   WS_B_BYTES
#define WS_CNORM_BYTES (NSTAGE * NCB * 4)
#define WS_MSE_OFF     (WS_CNORM_OFF + WS_CNORM_BYTES)
#define WS_IDX_OFF     (WS_MSE_OFF + 64)               // u16[NSTAGE][T_ROWS], 2 MiB

typedef __attribute__((ext_vector_type(8)))  short  s16x8;
typedef __attribute__((ext_vector_type(8)))  __bf16 bf16x8;
typedef __attribute__((ext_vector_type(4)))  float  f32x4;
typedef __attribute__((ext_vector_type(16))) float  f32x16;

__device__ __forceinline__ unsigned short f2bf(float f) {
  union { float f; unsigned u; } v; v.f = f;
  unsigned r = v.u + 0x7FFFu + ((v.u >> 16) & 1u);   // RNE
  return (unsigned short)(r >> 16);
}

// ---------------------------------------------------------------------------
// Preprocess (write-coalesced, R6). Phase 1: fp32 CB -> bf16 B-frag copy.
//   block b (0..1023): group g = b>>2 (32 codewords), s-quarter s0q = (b&3)*4.
//   thread: c32 = tid&31, sh = tid>>5 -> s = s0q + (sh>>1), hi = sh&1.
//   dst = wsb + g*16384 + s*1024 + hi*512 + c32*16 (contiguous 4KB per block).
// Phase 2: cnorm with coalesced reads + 32-thread shfl reduction.
// ---------------------------------------------------------------------------
__global__ void vq_prep(const float* __restrict__ CB, char* __restrict__ wsb,
                        float* __restrict__ cnorm) {
  const int tid = threadIdx.x;
  const int b   = blockIdx.x;
  // ---- phase 1: B-frag copy ----
  {
    const int g   = b >> 2;
    const int s0q = (b & 3) * 4;
    const int c32 = tid & 31;
    const int sh  = tid >> 5;
    const int s   = s0q + (sh >> 1);
    const int hi  = sh & 1;
    const int cw  = g * 32 + c32;          // global codeword (stage built in)
    const float* src = CB + (size_t)cw * DIM + 16 * s + 8 * hi;
    f32x4 a = *(const f32x4*)(src);
    f32x4 c = *(const f32x4*)(src + 4);
    s16x8 h;
#pragma unroll
    for (int e = 0; e < 4; ++e) { h[e] = (short)f2bf(a[e]); h[4 + e] = (short)f2bf(c[e]); }
    *(s16x8*)(wsb + (size_t)g * 16384 + s * 1024 + hi * 512 + c32 * 16) = h;
  }
  // ---- phase 2: cnorm ----
  {
    const int cwl = tid >> 5;
    const int j   = tid & 31;
    const int cw  = b * 8 + cwl;
    const float* src = CB + (size_t)cw * DIM + 8 * j;
    f32x4 a = *(const f32x4*)(src);
    f32x4 c = *(const f32x4*)(src + 4);
    float sq = a[0]*a[0] + a[1]*a[1] + a[2]*a[2] + a[3]*a[3]
             + c[0]*c[0] + c[1]*c[1] + c[2]*c[2] + c[3]*c[3];
#pragma unroll
    for (int m = 1; m <= 16; m <<= 1) sq += __shfl_xor(sq, m);   // 32-thread group
    if (j == 0) cnorm[cw] = sq;
  }
}

// ---------------------------------------------------------------------------
// Search kernel. 2 waves/block; wave owns 64 rows as TWO 32-row m-tiles;
// 4 blocks/CU (8 waves/CU).
// 32x32x16 MFMA layouts: A/B: lane l -> k = 8*(l>>5)+e; A row / B col = l&31.
// C/D: col = l&31, row = (reg&3) + 8*(reg>>2) + 4*(l>>5).
// acc starts at 0; -||c||^2/2 subtracted at pack so argmin dist ==
// argmax (r.c - cn/2); codeword index packed into low 10 mantissa bits ->
// fmax-only running argmax.
// ---------------------------------------------------------------------------
__global__ __launch_bounds__(NTHREADS, 2)
void vq_search(const float* __restrict__ X,
               const char* __restrict__ wsb, const float* __restrict__ cnorm,
               unsigned short* __restrict__ IDX, float* __restrict__ wsmse) {
  __shared__ __align__(16) char  lds_cb[2][CHUNK_BYTES];  // 32 KiB ring
  __shared__ unsigned short lds_idx[BLK_ROWS];            // 256 B
  __shared__ float lds_n[BLK_ROWS];                       // 512 B
  __shared__ float lds_msum[NWAVE];                       // 8 B

  const int tid  = threadIdx.x;
  const int wave = tid >> 6;           // 0..1
  const int lane = tid & 63;
  const int c32  = lane & 31;          // A row / B,D col within 32-tile
  const int hi   = lane >> 5;          // k-half (A,B) / row-offset (D)

  const int rowbase = blockIdx.x * BLK_ROWS + wave * WROWS;

  // ---- initial approximate residual = bf16(x), A-fragment layout ----
  // tile t: lane holds row rowbase + t*32 + c32; step s covers dims
  // d = 16*s + 8*hi + e, e=0..7
  bf16x8 af[2][16];
#pragma unroll
  for (int t = 0; t < 2; ++t) {
    const float* px = X + (size_t)(rowbase + t * 32 + c32) * DIM + 8 * hi;
    float s2 = 0.f;
#pragma unroll
    for (int s = 0; s < 16; ++s) {
      f32x4 a = *(const f32x4*)(px + 16 * s);
      f32x4 b = *(const f32x4*)(px + 16 * s + 4);
      bf16x8 tt;
#pragma unroll
      for (int e = 0; e < 4; ++e) {
        tt[e] = (__bf16)a[e]; tt[4 + e] = (__bf16)b[e];
        s2 += a[e] * a[e] + b[e] * b[e];
      }
      af[t][s] = tt;
    }
    // n0 = ||x||^2: lane's partial covers its k-half; pair with lane^32.
    float v = s2 + __shfl_xor(s2, 32);
    if (lane < 32) lds_n[wave * WROWS + t * 32 + c32] = v;
  }

  // ---- prologue: stage flat chunk 0 into slot 0 (8 segs/wave), drain ----
#pragma unroll
  for (int i = 0; i < 8; ++i) {
    const int seg = (wave * 8 + i) * 1024;
    __builtin_amdgcn_global_load_lds(
        (const __attribute__((address_space(1))) char*)(wsb + seg + lane * 16),
        (__attribute__((address_space(3))) char*)(&lds_cb[0][0] + seg),
        16, 0, 0);
  }
  asm volatile("s_waitcnt vmcnt(0)" ::: "memory");
  __builtin_amdgcn_sched_barrier(0);

#pragma unroll 1
  for (int st = 0; st < NSTAGE; ++st) {
    float mv[2][16];
#pragma unroll
    for (int t = 0; t < 2; ++t)
#pragma unroll
      for (int r = 0; r < 16; ++r) mv[t][r] = -3.402823466e38f;

#pragma unroll 1
    for (int ch = 0; ch < NCHUNK; ++ch) {
      const int gf = st * NCHUNK + ch;           // flat chunk 0..255

      // top-of-chunk barrier (2 waves only): buf[gf&1] fully staged — every
      // wave drained its own staging with vmcnt(0) before reaching it.
      __builtin_amdgcn_sched_barrier(0);
      __builtin_amdgcn_s_barrier();
      __builtin_amdgcn_sched_barrier(0);

      // issue staging for chunk gf+1 into buf[(gf+1)&1].
      // Safety: that buffer held chunk gf-1; both waves' reads of gf-1
      // preceded their bottom vmcnt+barrier(gf).
      if (gf + 1 < NGCH) {
        const char* src = wsb + (size_t)(gf + 1) * CHUNK_BYTES;
        char* dst = &lds_cb[(gf + 1) & 1][0];
#pragma unroll
        for (int i = 0; i < 8; ++i) {
          const int seg = (wave * 8 + i) * 1024;
          __builtin_amdgcn_global_load_lds(
              (const __attribute__((address_space(1))) char*)(src + seg + lane * 16),
              (__attribute__((address_space(3))) char*)(dst + seg),
              16, 0, 0);
        }
      }

      // cn: coalesced 128B global read, consumed only at pack time
      const float cnv = cnorm[gf * CHUNK_CW + c32];

      f32x16 acc0, acc1;
#pragma unroll
      for (int r = 0; r < 16; ++r) { acc0[r] = 0.f; acc1[r] = 0.f; }

      const char* buf = &lds_cb[gf & 1][0] + lane * 16;
      __builtin_amdgcn_s_setprio(1);
#pragma unroll
      for (int s = 0; s < 16; ++s) {
        bf16x8 b = *(const bf16x8*)(buf + s * 1024);   // linear, conflict-free
        acc0 = __builtin_amdgcn_mfma_f32_32x32x16_bf16(af[0][s], b, acc0, 0, 0, 0);
        acc1 = __builtin_amdgcn_mfma_f32_32x32x16_bf16(af[1][s], b, acc1, 0, 0, 0);
      }
      __builtin_amdgcn_s_setprio(0);

      // pack: p = (r.c - cn/2) with codeword index in low 10 mantissa bits
      const float cnh = 0.5f * cnv;
      const unsigned col = (unsigned)(ch * CHUNK_CW + c32);
#pragma unroll
      for (int r = 0; r < 16; ++r) {
        union { float f; unsigned u; } p0, p1;
        p0.f = acc0[r] - cnh; p0.u = (p0.u & 0xFFFFFC00u) | col;
        p1.f = acc1[r] - cnh; p1.u = (p1.u & 0xFFFFFC00u) | col;
        mv[0][r] = fmaxf(mv[0][r], p0.f);
        mv[1][r] = fmaxf(mv[1][r], p1.f);
      }

      // bottom: drain own staging so barrier(gf+1) implies buf fully staged
      asm volatile("s_waitcnt vmcnt(0)" ::: "memory");
      __builtin_amdgcn_sched_barrier(0);
    }

    // ---- cross-lane argmax + ||r||^2 recursion ----
    // (t,r): row = t*32 + (r&3) + 8*(r>>2) + 4*hi ; reduce over the 32 cols
    float msum = 0.f;
#pragma unroll
    for (int t = 0; t < 2; ++t)
#pragma unroll
      for (int r = 0; r < 16; ++r) {
        float v = mv[t][r];
#pragma unroll
        for (int m = 1; m <= 16; m <<= 1) v = fmaxf(v, __shfl_xor(v, m));
        union { float f; unsigned u; } w; w.f = v;
        const float vtrue = __builtin_bit_cast(float, w.u & 0xFFFFFC00u);
        const int   row   = t * 32 + (r & 3) + 8 * (r >> 2) + 4 * hi;
        const int   wrow  = wave * WROWS + row;
        const float n_new = lds_n[wrow] - 2.0f * vtrue;   // min-dist identity
        msum += n_new;
        if (c32 == 0) {
          lds_n[wrow]   = n_new;
          const int ix = (int)(w.u & 1023u);
          lds_idx[wrow] = (unsigned short)ix;
          IDX[st * T_ROWS + rowbase + row] = (unsigned short)ix;
        }
      }
    // msum uniform within each 32-lane half; halves cover disjoint rows
    msum += __shfl_xor(msum, 32);
    if (lane == 0) lds_msum[wave] = msum;

    if (st != NSTAGE - 1) {
      // ---- approximate af update (ranking only) from the B-layout copy:
      //      dims d=16s+8hi+e of codeword idx live at
      //      wsb + st*512K + (idx>>5)*16384 + s*1024 + hi*512 + (idx&31)*16
#pragma unroll
      for (int t = 0; t < 2; ++t) {
        const int idx = (int)lds_idx[wave * WROWS + t * 32 + c32];
        const char* q = wsb + (size_t)st * NCB * 512
                      + (size_t)(idx >> 5) * 16384 + hi * 512 + (idx & 31) * 16;
#pragma unroll
        for (int s = 0; s < 16; ++s) {
          bf16x8 qb = *(const bf16x8*)(q + s * 1024);
          bf16x8 tt = af[t][s];
#pragma unroll
          for (int e = 0; e < 8; ++e)
            tt[e] = (__bf16)((float)tt[e] - (float)qb[e]);
          af[t][s] = tt;
        }
      }
    }

    // stage-end barrier (2 waves): orders lds_msum before the block reduce
    __builtin_amdgcn_s_barrier();

    // block-level MSE reduction: 1 atomic per block per stage
    if (wave == 0) {
      float v = (lane < NWAVE) ? lds_msum[lane] : 0.f;
      v += __shfl_xor(v, 1);
      if (lane == 0) atomicAdd(wsmse + st, v);
    }
  }
}

// ---------------------------------------------------------------------------
// Recon kernel: OUT[row] = sum of the 8 chosen bf16 codewords, read from the
// B-layout copy. 8 threads/row; thread g covers dims g*32..g*32+31:
//   dim d = g*32 + k*8  ->  s = 2g + (k>>1), hi = k&1
// ---------------------------------------------------------------------------
__global__ __launch_bounds__(256)
void vq_recon(const char* __restrict__ wsb, const unsigned short* __restrict__ IDX,
              float* __restrict__ OUT) {
  const int tid = threadIdx.x;
  const int row = blockIdx.x * (256 / 8) + (tid >> 3);
  const int g   = tid & 7;             // dims g*32 .. g*32+31

  int idxs[NSTAGE];
#pragma unroll
  for (int st = 0; st < NSTAGE; ++st) idxs[st] = IDX[st * T_ROWS + row];

  float a[32];
#pragma unroll
  for (int d = 0; d < 32; ++d) a[d] = 0.f;

#pragma unroll
  for (int st = 0; st < NSTAGE; ++st) {
    const char* q = wsb + (size_t)st * NCB * 512
                  + (size_t)(idxs[st] >> 5) * 16384 + (idxs[st] & 31) * 16;
#pragma unroll
    for (int k = 0; k < 4; ++k) {
      const int s  = 2 * g + (k >> 1);
      const int h2 = (k & 1);
      bf16x8 qb = *(const bf16x8*)(q + s * 1024 + h2 * 512);
#pragma unroll
      for (int e = 0; e < 8; ++e) a[k * 8 + e] += (float)qb[e];
    }
  }

  float* po = OUT + (size_t)row * DIM + g * 32;
#pragma unroll
  for (int m = 0; m < 8; ++m) {
    f32x4 o = {a[4 * m], a[4 * m + 1], a[4 * m + 2], a[4 * m + 3]};
    *(f32x4*)(po + 4 * m) = o;
  }
}

__global__ void vq_fin(const float* __restrict__ wsmse, float* __restrict__ OUT) {
  const int i = threadIdx.x;
  if (i < NSTAGE) {
    OUT[(size_t)T_ROWS * DIM + i] = wsmse[i] * (1.0f / ((float)T_ROWS * (float)DIM));
  }
}

extern "C" void kernel_launch(void* const* d_in, const int* in_sizes, int n_in,
                              void* d_out, int out_size, void* d_ws, size_t ws_size,
                              hipStream_t stream) {
  (void)in_sizes; (void)n_in; (void)out_size; (void)ws_size;
  const float* X  = (const float*)d_in[0];
  const float* CB = (const float*)d_in[1];
  float* OUT = (float*)d_out;
  char*  wsb   = (char*)d_ws;
  float* cnorm = (float*)((char*)d_ws + WS_CNORM_OFF);
  float* wsmse = (float*)((char*)d_ws + WS_MSE_OFF);
  unsigned short* IDX = (unsigned short*)((char*)d_ws + WS_IDX_OFF);

  hipMemsetAsync(wsmse, 0, NSTAGE * sizeof(float), stream);
  hipLaunchKernelGGL(vq_prep, dim3(1024), dim3(256), 0, stream,
                     CB, wsb, cnorm);
  hipLaunchKernelGGL(vq_search, dim3(T_ROWS / BLK_ROWS), dim3(NTHREADS), 0, stream,
                     X, wsb, cnorm, IDX, wsmse);
  hipLaunchKernelGGL(vq_recon, dim3(T_ROWS / (256 / 8)), dim3(256), 0, stream,
                     wsb, IDX, OUT);
  hipLaunchKernelGGL(vq_fin, dim3(1), dim3(64), 0, stream, wsmse, OUT);
}